// Round 1
// baseline (1172.581 us; speedup 1.0000x reference)
//
#include <hip/hip_runtime.h>

#define C_DIM  384
#define HEADS  6
#define HD     64
#define FF_DIM 1536
#define LN_EPS 1e-3f

// ---------------------------------------------------------------------------
// Tiled FP32 GEMM: C[M,N] = A[M,K] @ B[K,N] (+ bias) (optional ReLU)
// 64x64 tile per 256-thread block, each thread computes 4x4.
// M % 64 == 0, N % 64 == 0, K % 16 == 0 (true for all shapes here).
// ---------------------------------------------------------------------------
template<int BIAS, int RELU>
__global__ __launch_bounds__(256)
void sgemm_kernel(const float* __restrict__ A, const float* __restrict__ B,
                  const float* __restrict__ bias, float* __restrict__ Cout,
                  int M, int N, int K)
{
    __shared__ float As[16][65];   // As[k][m], +1 pad
    __shared__ float Bs[16][65];   // Bs[k][n], +1 pad
    const int tid = threadIdx.x;
    const int tm  = tid >> 4;      // 0..15
    const int tn  = tid & 15;      // 0..15
    const int row0 = blockIdx.y * 64;
    const int col0 = blockIdx.x * 64;

    float acc[4][4] = {};

    for (int k0 = 0; k0 < K; k0 += 16) {
        #pragma unroll
        for (int i = 0; i < 4; ++i) {
            int idx = tid + i * 256;       // 0..1023
            int m   = idx >> 4;            // 0..63
            int kk  = idx & 15;
            As[kk][m] = A[(size_t)(row0 + m) * K + (k0 + kk)];
        }
        #pragma unroll
        for (int i = 0; i < 4; ++i) {
            int idx = tid + i * 256;
            int kk  = idx >> 6;            // 0..15
            int n   = idx & 63;
            Bs[kk][n] = B[(size_t)(k0 + kk) * N + (col0 + n)];
        }
        __syncthreads();
        #pragma unroll
        for (int kk = 0; kk < 16; ++kk) {
            float a[4], b[4];
            #pragma unroll
            for (int i = 0; i < 4; ++i) a[i] = As[kk][tm * 4 + i];
            #pragma unroll
            for (int j = 0; j < 4; ++j) b[j] = Bs[kk][tn * 4 + j];
            #pragma unroll
            for (int i = 0; i < 4; ++i)
                #pragma unroll
                for (int j = 0; j < 4; ++j)
                    acc[i][j] = fmaf(a[i], b[j], acc[i][j]);
        }
        __syncthreads();
    }

    #pragma unroll
    for (int i = 0; i < 4; ++i) {
        const size_t r = (size_t)(row0 + tm * 4 + i);
        #pragma unroll
        for (int j = 0; j < 4; ++j) {
            const int c = col0 + tn * 4 + j;
            float v = acc[i][j];
            if (BIAS) v += bias[c];
            if (RELU) v = fmaxf(v, 0.0f);
            Cout[r * N + c] = v;
        }
    }
}

// ---------------------------------------------------------------------------
// Flash-style causal attention, fp32.
// One 256-thread block per (q-tile of 64 rows, head, batch).
// Q,K,V stored as [B*T, C] with head h at columns h*64..h*64+63.
// K-tile LDS buffer is reused to hold P (exp scores) for the PV GEMM,
// keeping static LDS at 3*64*65*4 = 49.9 KB.
// ---------------------------------------------------------------------------
__global__ __launch_bounds__(256)
void attn_kernel(const float* __restrict__ Q, const float* __restrict__ K,
                 const float* __restrict__ V, float* __restrict__ O, int T)
{
    __shared__ float Qs[64][65];
    __shared__ float KPs[64][65];   // K tile, later reused for P
    __shared__ float Vs[64][65];

    const int tid = threadIdx.x;
    const int tm  = tid >> 4;       // 0..15 (row group)
    const int tn  = tid & 15;       // 0..15 (col group)
    const int qt  = blockIdx.x;
    const int h   = blockIdx.y;
    const int b   = blockIdx.z;
    const size_t base = ((size_t)b * T) * C_DIM + (size_t)h * HD;

    // load Q tile (64 rows x 64 dims), coalesced
    #pragma unroll
    for (int i = 0; i < 16; ++i) {
        int idx = i * 256 + tid;
        int r = idx >> 6, d = idx & 63;
        Qs[r][d] = Q[base + (size_t)(qt * 64 + r) * C_DIM + d];
    }

    float acc[4][4] = {};
    float m_i[4], l_i[4];
    #pragma unroll
    for (int i = 0; i < 4; ++i) { m_i[i] = -1e30f; l_i[i] = 0.0f; }

    __syncthreads();

    for (int kt = 0; kt <= qt; ++kt) {
        // load K and V tiles
        #pragma unroll
        for (int i = 0; i < 16; ++i) {
            int idx = i * 256 + tid;
            int r = idx >> 6, d = idx & 63;
            size_t g = base + (size_t)(kt * 64 + r) * C_DIM + d;
            KPs[r][d] = K[g];
            Vs[r][d]  = V[g];
        }
        __syncthreads();

        // S = Q @ K^T   (thread owns rows tm*4.., cols tn*4..)
        float s[4][4] = {};
        #pragma unroll 8
        for (int d = 0; d < 64; ++d) {
            float a[4], bb[4];
            #pragma unroll
            for (int i = 0; i < 4; ++i) a[i] = Qs[tm * 4 + i][d];
            #pragma unroll
            for (int j = 0; j < 4; ++j) bb[j] = KPs[tn * 4 + j][d];
            #pragma unroll
            for (int i = 0; i < 4; ++i)
                #pragma unroll
                for (int j = 0; j < 4; ++j)
                    s[i][j] = fmaf(a[i], bb[j], s[i][j]);
        }

        // online softmax per row (row owned by 16 consecutive lanes)
        float p[4][4];
        #pragma unroll
        for (int i = 0; i < 4; ++i) {
            const int qr = qt * 64 + tm * 4 + i;
            float rowmax = -1e30f;
            #pragma unroll
            for (int j = 0; j < 4; ++j) {
                const int kc = kt * 64 + tn * 4 + j;
                float sv = s[i][j] * 0.125f;    // 1/sqrt(64)
                if (kc > qr) sv = -1e30f;       // causal mask
                s[i][j] = sv;
                rowmax = fmaxf(rowmax, sv);
            }
            rowmax = fmaxf(rowmax, __shfl_xor(rowmax, 1));
            rowmax = fmaxf(rowmax, __shfl_xor(rowmax, 2));
            rowmax = fmaxf(rowmax, __shfl_xor(rowmax, 4));
            rowmax = fmaxf(rowmax, __shfl_xor(rowmax, 8));
            const float mnew = fmaxf(m_i[i], rowmax);
            const float corr = __expf(m_i[i] - mnew);
            float lsum = 0.0f;
            #pragma unroll
            for (int j = 0; j < 4; ++j) {
                float pv = __expf(s[i][j] - mnew);
                p[i][j] = pv;
                lsum += pv;
            }
            lsum += __shfl_xor(lsum, 1);
            lsum += __shfl_xor(lsum, 2);
            lsum += __shfl_xor(lsum, 4);
            lsum += __shfl_xor(lsum, 8);
            l_i[i] = l_i[i] * corr + lsum;
            m_i[i] = mnew;
            #pragma unroll
            for (int j = 0; j < 4; ++j) acc[i][j] *= corr;
        }

        __syncthreads();            // everyone done reading K tile
        #pragma unroll
        for (int i = 0; i < 4; ++i)
            #pragma unroll
            for (int j = 0; j < 4; ++j)
                KPs[tm * 4 + i][tn * 4 + j] = p[i][j];
        __syncthreads();            // P visible

        // acc += P @ V   (out cols are head dims tn*4..)
        #pragma unroll 8
        for (int k = 0; k < 64; ++k) {
            float a[4], bb[4];
            #pragma unroll
            for (int i = 0; i < 4; ++i) a[i] = KPs[tm * 4 + i][k];
            #pragma unroll
            for (int j = 0; j < 4; ++j) bb[j] = Vs[k][tn * 4 + j];
            #pragma unroll
            for (int i = 0; i < 4; ++i)
                #pragma unroll
                for (int j = 0; j < 4; ++j)
                    acc[i][j] = fmaf(a[i], bb[j], acc[i][j]);
        }
        __syncthreads();            // before next tile overwrite
    }

    #pragma unroll
    for (int i = 0; i < 4; ++i) {
        const float inv_l = 1.0f / l_i[i];
        #pragma unroll
        for (int j = 0; j < 4; ++j) {
            O[base + (size_t)(qt * 64 + tm * 4 + i) * C_DIM + (tn * 4 + j)] =
                acc[i][j] * inv_l;
        }
    }
}

// ---------------------------------------------------------------------------
// Fused residual add + LayerNorm over rows of length 384.
// One wave per row, 4 rows per 256-thread block. out = LN(A + R) * g + b.
// ---------------------------------------------------------------------------
__global__ __launch_bounds__(256)
void ln_residual_kernel(const float* __restrict__ A, const float* __restrict__ R,
                        const float* __restrict__ gamma, const float* __restrict__ beta,
                        float* __restrict__ out, int Mrows)
{
    const int lane = threadIdx.x & 63;
    const int wv   = threadIdx.x >> 6;
    const int row  = blockIdx.x * 4 + wv;
    if (row >= Mrows) return;
    const size_t off = (size_t)row * C_DIM;

    float v[6];
    float sum = 0.0f;
    #pragma unroll
    for (int j = 0; j < 6; ++j) {
        const int c = lane + 64 * j;
        v[j] = A[off + c] + R[off + c];
        sum += v[j];
    }
    #pragma unroll
    for (int o = 1; o < 64; o <<= 1) sum += __shfl_xor(sum, o);
    const float mu = sum * (1.0f / C_DIM);

    float sq = 0.0f;
    #pragma unroll
    for (int j = 0; j < 6; ++j) { const float d = v[j] - mu; sq = fmaf(d, d, sq); }
    #pragma unroll
    for (int o = 1; o < 64; o <<= 1) sq += __shfl_xor(sq, o);
    const float rstd = rsqrtf(sq * (1.0f / C_DIM) + LN_EPS);

    #pragma unroll
    for (int j = 0; j < 6; ++j) {
        const int c = lane + 64 * j;
        out[off + c] = (v[j] - mu) * rstd * gamma[c] + beta[c];
    }
}

// ---------------------------------------------------------------------------
extern "C" void kernel_launch(void* const* d_in, const int* in_sizes, int n_in,
                              void* d_out, int out_size, void* d_ws, size_t ws_size,
                              hipStream_t stream)
{
    const float* x   = (const float*)d_in[0];
    const float* Wq  = (const float*)d_in[1];
    const float* Wk  = (const float*)d_in[2];
    const float* Wv  = (const float*)d_in[3];
    const float* Wo  = (const float*)d_in[4];
    const float* bo  = (const float*)d_in[5];
    const float* W1  = (const float*)d_in[6];
    const float* b1  = (const float*)d_in[7];
    const float* W2  = (const float*)d_in[8];
    const float* b2  = (const float*)d_in[9];
    const float* g1  = (const float*)d_in[10];
    const float* be1 = (const float*)d_in[11];
    const float* g2  = (const float*)d_in[12];
    const float* be2 = (const float*)d_in[13];
    float* out = (float*)d_out;

    const int B = 4, T = 2048;
    const int M = B * T;                       // 8192 token rows
    const size_t MC = (size_t)M * C_DIM;       // 3,145,728 floats

    // workspace layout (floats); h1 (M*FF = 4*MC) aliases q/k/v/att which are
    // dead by the time FF1 runs. Total = 6*MC floats = 75.5 MB.
    float* ws  = (float*)d_ws;
    float* q   = ws;            // MC
    float* k   = ws + 1 * MC;   // MC
    float* v   = ws + 2 * MC;   // MC
    float* att = ws + 3 * MC;   // MC
    float* y   = ws + 4 * MC;   // MC  (attn proj out, later FF2 out)
    float* x1  = ws + 5 * MC;   // MC  (post-LN1 activations)
    float* h1  = ws;            // M * FF_DIM = 4*MC, aliases q..att

    dim3 blk(256);
    dim3 g_cc(C_DIM / 64, M / 64);     // N=384 GEMMs
    dim3 g_ff1(FF_DIM / 64, M / 64);   // N=1536 GEMM

    // QKV projections
    sgemm_kernel<0, 0><<<g_cc, blk, 0, stream>>>(x, Wq, nullptr, q, M, C_DIM, C_DIM);
    sgemm_kernel<0, 0><<<g_cc, blk, 0, stream>>>(x, Wk, nullptr, k, M, C_DIM, C_DIM);
    sgemm_kernel<0, 0><<<g_cc, blk, 0, stream>>>(x, Wv, nullptr, v, M, C_DIM, C_DIM);

    // causal attention
    dim3 g_att(T / 64, HEADS, B);
    attn_kernel<<<g_att, blk, 0, stream>>>(q, k, v, att, T);

    // output projection + bias
    sgemm_kernel<1, 0><<<g_cc, blk, 0, stream>>>(att, Wo, bo, y, M, C_DIM, C_DIM);

    // x1 = LN(x + y)
    ln_residual_kernel<<<dim3(M / 4), blk, 0, stream>>>(x, y, g1, be1, x1, M);

    // h1 = relu(x1 @ W1 + b1)
    sgemm_kernel<1, 1><<<g_ff1, blk, 0, stream>>>(x1, W1, b1, h1, M, FF_DIM, C_DIM);

    // y2 = h1 @ W2 + b2   (into y)
    sgemm_kernel<1, 0><<<g_cc, blk, 0, stream>>>(h1, W2, b2, y, M, C_DIM, FF_DIM);

    // out = LN(x1 + y2)
    ln_residual_kernel<<<dim3(M / 4), blk, 0, stream>>>(x1, y, g2, be2, out, M);
}

// Round 2
// 267.621 us; speedup vs baseline: 4.3815x; 4.3815x over previous
//
#include <hip/hip_runtime.h>

#define C_DIM  384
#define HEADS  6
#define HD     64
#define FF_DIM 1536
#define LN_EPS 1e-3f

typedef __attribute__((ext_vector_type(4))) float          f32x4;
typedef __attribute__((ext_vector_type(4))) float          float4_t;
typedef __attribute__((ext_vector_type(8))) short          bfrag;     // 8 bf16
typedef __attribute__((ext_vector_type(4))) unsigned short ushort4_t;
typedef __attribute__((ext_vector_type(8))) unsigned short ushort8_t;

__device__ inline unsigned short f2bf(float f) {
    unsigned int u = __builtin_bit_cast(unsigned int, f);
    u += 0x7fff + ((u >> 16) & 1);          // RNE
    return (unsigned short)(u >> 16);
}

// ---------------------------------------------------------------------------
// weight conversion kernels
// ---------------------------------------------------------------------------
__global__ void pack_qkv_kernel(const float* __restrict__ Wq, const float* __restrict__ Wk,
                                const float* __restrict__ Wv, unsigned short* __restrict__ out)
{
    int idx = blockIdx.x * 256 + threadIdx.x;          // over 384*1152
    if (idx >= C_DIM * 3 * C_DIM) return;
    int r = idx / (3 * C_DIM), cc = idx % (3 * C_DIM);
    int sel = cc / C_DIM, c = cc % C_DIM;
    const float* W = sel == 0 ? Wq : (sel == 1 ? Wk : Wv);
    out[idx] = f2bf(W[r * C_DIM + c]);
}

__global__ void cvt_bf16_kernel(const float* __restrict__ in, unsigned short* __restrict__ out, int n)
{
    int idx = blockIdx.x * 256 + threadIdx.x;
    if (idx < n) out[idx] = f2bf(in[idx]);
}

// ---------------------------------------------------------------------------
// bf16 MFMA GEMM: C[M,N] = A[M,K] @ B[K,N] (+bias) (+relu)
// 64x64 tile / 256 threads (4 waves in 2x2), BK=64, mfma_f32_16x16x32_bf16.
// A fp32 or bf16 (template); B bf16 [K][N]; C fp32 or bf16.
// ---------------------------------------------------------------------------
template<int ABF16, int OBF16, int BIAS, int RELU>
__global__ __launch_bounds__(256)
void gemm_bf16(const void* __restrict__ Av, const unsigned short* __restrict__ B,
               const float* __restrict__ bias, void* __restrict__ Cv,
               int M, int N, int K, int lda, int ldb, int ldc)
{
    __shared__ __align__(16) unsigned short As[64][72];   // [m][k], pad to 144B rows
    __shared__ __align__(16) unsigned short Bt[64][72];   // [n][k] (B transposed)

    const int t    = threadIdx.x;
    const int lane = t & 63;
    const int w    = t >> 6;
    const int wr   = w >> 1, wc = w & 1;
    const int ln16 = lane & 15, hi16 = lane >> 4;
    const int row0 = blockIdx.y * 64;
    const int col0 = blockIdx.x * 64;

    f32x4 acc[2][2] = {};

    for (int k0 = 0; k0 < K; k0 += 64) {
        // ---- stage A (64 rows x 64 k) ----
        if (ABF16) {
            const unsigned short* A = (const unsigned short*)Av;
            #pragma unroll
            for (int i = 0; i < 2; ++i) {
                int idx = i * 256 + t;
                int r = idx >> 3, g = idx & 7;
                ushort8_t v = *(const ushort8_t*)&A[(size_t)(row0 + r) * lda + k0 + g * 8];
                *(ushort8_t*)&As[r][g * 8] = v;
            }
        } else {
            const float* A = (const float*)Av;
            #pragma unroll
            for (int i = 0; i < 4; ++i) {
                int idx = i * 256 + t;
                int r = idx >> 4, g = idx & 15;
                float4_t v = *(const float4_t*)&A[(size_t)(row0 + r) * lda + k0 + g * 4];
                ushort4_t o = { f2bf(v.x), f2bf(v.y), f2bf(v.z), f2bf(v.w) };
                *(ushort4_t*)&As[r][g * 4] = o;
            }
        }
        // ---- stage B transposed (64 k x 64 n -> Bt[n][k]) ----
        {
            int p = t >> 4, q = t & 15;           // k-group, n-group
            int kk = p * 4, nn = q * 4;
            ushort4_t bj[4];
            #pragma unroll
            for (int j = 0; j < 4; ++j)
                bj[j] = *(const ushort4_t*)&B[(size_t)(k0 + kk + j) * ldb + col0 + nn];
            #pragma unroll
            for (int c = 0; c < 4; ++c) {
                ushort4_t wv = { bj[0][c], bj[1][c], bj[2][c], bj[3][c] };
                *(ushort4_t*)&Bt[nn + c][kk] = wv;
            }
        }
        __syncthreads();

        // ---- compute: per wave 32x32 out = 2x2 fragments ----
        #pragma unroll
        for (int ks = 0; ks < 2; ++ks) {
            bfrag a0 = *(const bfrag*)&As[wr * 32 +  0 + ln16][ks * 32 + 8 * hi16];
            bfrag a1 = *(const bfrag*)&As[wr * 32 + 16 + ln16][ks * 32 + 8 * hi16];
            bfrag b0 = *(const bfrag*)&Bt[wc * 32 +  0 + ln16][ks * 32 + 8 * hi16];
            bfrag b1 = *(const bfrag*)&Bt[wc * 32 + 16 + ln16][ks * 32 + 8 * hi16];
            acc[0][0] = __builtin_amdgcn_mfma_f32_16x16x32_bf16(a0, b0, acc[0][0], 0, 0, 0);
            acc[0][1] = __builtin_amdgcn_mfma_f32_16x16x32_bf16(a0, b1, acc[0][1], 0, 0, 0);
            acc[1][0] = __builtin_amdgcn_mfma_f32_16x16x32_bf16(a1, b0, acc[1][0], 0, 0, 0);
            acc[1][1] = __builtin_amdgcn_mfma_f32_16x16x32_bf16(a1, b1, acc[1][1], 0, 0, 0);
        }
        __syncthreads();
    }

    // ---- epilogue ----
    #pragma unroll
    for (int mt = 0; mt < 2; ++mt) {
        #pragma unroll
        for (int nt = 0; nt < 2; ++nt) {
            const int col = col0 + wc * 32 + nt * 16 + ln16;
            const float bv = BIAS ? bias[col] : 0.0f;
            #pragma unroll
            for (int b = 0; b < 4; ++b) {
                const int row = row0 + wr * 32 + mt * 16 + hi16 * 4 + b;
                float v = acc[mt][nt][b] + bv;
                if (RELU) v = fmaxf(v, 0.0f);
                if (OBF16) ((unsigned short*)Cv)[(size_t)row * ldc + col] = f2bf(v);
                else       ((float*)Cv)[(size_t)row * ldc + col] = v;
            }
        }
    }
}

// ---------------------------------------------------------------------------
// Flash-style causal attention, bf16 MFMA.
// Block: 256 thr = 4 waves; one 64-row q-tile x one head x one batch.
// qkv: bf16 [M][1152] (q | k | v each 384 cols, head h at h*64).
// Out: att bf16 [M][384].
// ---------------------------------------------------------------------------
__global__ __launch_bounds__(256)
void attn_mfma_kernel(const unsigned short* __restrict__ qkv,
                      unsigned short* __restrict__ att, int T)
{
    __shared__ __align__(16) unsigned short Qs[64][72];
    __shared__ __align__(16) unsigned short Ks[64][72];
    __shared__ __align__(16) unsigned short Vt[64][72];   // [d][k]
    __shared__ __align__(16) unsigned short Ps[64][72];   // [qrow][key], wave-private strips

    const int t    = threadIdx.x;
    const int lane = t & 63;
    const int w    = t >> 6;
    const int ln16 = lane & 15, hi16 = lane >> 4;
    const int qt   = blockIdx.x;
    const int h    = blockIdx.y;
    const int bb   = blockIdx.z;
    const size_t rowstride = 3 * C_DIM;      // 1152
    const size_t tokQ = (size_t)bb * T + qt * 64;

    // ---- load Q tile ----
    #pragma unroll
    for (int i = 0; i < 2; ++i) {
        int idx = i * 256 + t;
        int r = idx >> 3, g = idx & 7;
        ushort8_t v = *(const ushort8_t*)&qkv[(tokQ + r) * rowstride + h * HD + g * 8];
        *(ushort8_t*)&Qs[r][g * 8] = v;
    }
    __syncthreads();

    // Q fragments for this wave's 16-row strip (held for whole kernel)
    bfrag qfrag[2];
    #pragma unroll
    for (int ks = 0; ks < 2; ++ks)
        qfrag[ks] = *(const bfrag*)&Qs[w * 16 + ln16][ks * 32 + 8 * hi16];

    f32x4 acc[4] = {};
    float m_i[4], l_i[4];
    #pragma unroll
    for (int b = 0; b < 4; ++b) { m_i[b] = -1e30f; l_i[b] = 0.0f; }

    for (int kt = 0; kt <= qt; ++kt) {
        const size_t tokK = (size_t)bb * T + kt * 64;
        __syncthreads();   // previous iteration's reads done before overwrite
        // ---- stage K tile ----
        #pragma unroll
        for (int i = 0; i < 2; ++i) {
            int idx = i * 256 + t;
            int r = idx >> 3, g = idx & 7;
            ushort8_t v = *(const ushort8_t*)&qkv[(tokK + r) * rowstride + C_DIM + h * HD + g * 8];
            *(ushort8_t*)&Ks[r][g * 8] = v;
        }
        // ---- stage V tile transposed ----
        {
            int p = t >> 4, q = t & 15;
            int kk = p * 4, dd = q * 4;
            ushort4_t vr[4];
            #pragma unroll
            for (int j = 0; j < 4; ++j)
                vr[j] = *(const ushort4_t*)&qkv[(tokK + kk + j) * rowstride + 2 * C_DIM + h * HD + dd];
            #pragma unroll
            for (int c = 0; c < 4; ++c) {
                ushort4_t wv = { vr[0][c], vr[1][c], vr[2][c], vr[3][c] };
                *(ushort4_t*)&Vt[dd + c][kk] = wv;
            }
        }
        __syncthreads();

        // ---- S = Q @ K^T  (wave strip: 16 x 64) ----
        f32x4 sfrag[4] = {};
        #pragma unroll
        for (int jt = 0; jt < 4; ++jt) {
            #pragma unroll
            for (int ks = 0; ks < 2; ++ks) {
                bfrag kf = *(const bfrag*)&Ks[jt * 16 + ln16][ks * 32 + 8 * hi16];
                sfrag[jt] = __builtin_amdgcn_mfma_f32_16x16x32_bf16(qfrag[ks], kf, sfrag[jt], 0, 0, 0);
            }
        }

        // ---- online softmax (rows i = hi16*4+b, owned by 16-lane groups) ----
        float pb[4][4];   // [jt][b]
        float corr[4];
        const bool diag = (kt == qt);
        #pragma unroll
        for (int b = 0; b < 4; ++b) {
            const int qr = qt * 64 + w * 16 + hi16 * 4 + b;
            float mx = -1e30f;
            #pragma unroll
            for (int jt = 0; jt < 4; ++jt) {
                float sv = sfrag[jt][b] * 0.125f;
                if (diag) {
                    const int kc = kt * 64 + jt * 16 + ln16;
                    if (kc > qr) sv = -1e30f;
                }
                pb[jt][b] = sv;
                mx = fmaxf(mx, sv);
            }
            mx = fmaxf(mx, __shfl_xor(mx, 1));
            mx = fmaxf(mx, __shfl_xor(mx, 2));
            mx = fmaxf(mx, __shfl_xor(mx, 4));
            mx = fmaxf(mx, __shfl_xor(mx, 8));
            const float mnew = fmaxf(m_i[b], mx);
            corr[b] = __expf(m_i[b] - mnew);
            m_i[b] = mnew;
            float lsum = 0.0f;
            #pragma unroll
            for (int jt = 0; jt < 4; ++jt) {
                float pv = __expf(pb[jt][b] - mnew);
                pb[jt][b] = pv;
                lsum += pv;
            }
            lsum += __shfl_xor(lsum, 1);
            lsum += __shfl_xor(lsum, 2);
            lsum += __shfl_xor(lsum, 4);
            lsum += __shfl_xor(lsum, 8);
            l_i[b] = l_i[b] * corr[b] + lsum;
        }
        // rescale accumulators
        #pragma unroll
        for (int dt = 0; dt < 4; ++dt)
            #pragma unroll
            for (int b = 0; b < 4; ++b)
                acc[dt][b] *= corr[b];

        // ---- write P (wave-private strip; no barrier needed) ----
        #pragma unroll
        for (int jt = 0; jt < 4; ++jt)
            #pragma unroll
            for (int b = 0; b < 4; ++b)
                Ps[w * 16 + hi16 * 4 + b][jt * 16 + ln16] = f2bf(pb[jt][b]);

        // ---- acc += P @ V ----
        #pragma unroll
        for (int ks = 0; ks < 2; ++ks) {
            bfrag pf = *(const bfrag*)&Ps[w * 16 + ln16][ks * 32 + 8 * hi16];
            #pragma unroll
            for (int dt = 0; dt < 4; ++dt) {
                bfrag vf = *(const bfrag*)&Vt[dt * 16 + ln16][ks * 32 + 8 * hi16];
                acc[dt] = __builtin_amdgcn_mfma_f32_16x16x32_bf16(pf, vf, acc[dt], 0, 0, 0);
            }
        }
    }

    // ---- epilogue ----
    #pragma unroll
    for (int dt = 0; dt < 4; ++dt) {
        #pragma unroll
        for (int b = 0; b < 4; ++b) {
            const int row = qt * 64 + w * 16 + hi16 * 4 + b;
            const float v = acc[dt][b] / l_i[b];
            att[((size_t)bb * T + row) * C_DIM + h * HD + dt * 16 + ln16] = f2bf(v);
        }
    }
}

// ---------------------------------------------------------------------------
// Fused residual add + LayerNorm (fp32), rows of 384.
// ---------------------------------------------------------------------------
__global__ __launch_bounds__(256)
void ln_residual_kernel(const float* __restrict__ A, const float* __restrict__ R,
                        const float* __restrict__ gamma, const float* __restrict__ beta,
                        float* __restrict__ out, int Mrows)
{
    const int lane = threadIdx.x & 63;
    const int wv   = threadIdx.x >> 6;
    const int row  = blockIdx.x * 4 + wv;
    if (row >= Mrows) return;
    const size_t off = (size_t)row * C_DIM;

    float v[6];
    float sum = 0.0f;
    #pragma unroll
    for (int j = 0; j < 6; ++j) {
        const int c = lane + 64 * j;
        v[j] = A[off + c] + R[off + c];
        sum += v[j];
    }
    #pragma unroll
    for (int o = 1; o < 64; o <<= 1) sum += __shfl_xor(sum, o);
    const float mu = sum * (1.0f / C_DIM);

    float sq = 0.0f;
    #pragma unroll
    for (int j = 0; j < 6; ++j) { const float d = v[j] - mu; sq = fmaf(d, d, sq); }
    #pragma unroll
    for (int o = 1; o < 64; o <<= 1) sq += __shfl_xor(sq, o);
    const float rstd = rsqrtf(sq * (1.0f / C_DIM) + LN_EPS);

    #pragma unroll
    for (int j = 0; j < 6; ++j) {
        const int c = lane + 64 * j;
        out[off + c] = (v[j] - mu) * rstd * gamma[c] + beta[c];
    }
}

// ---------------------------------------------------------------------------
extern "C" void kernel_launch(void* const* d_in, const int* in_sizes, int n_in,
                              void* d_out, int out_size, void* d_ws, size_t ws_size,
                              hipStream_t stream)
{
    const float* x   = (const float*)d_in[0];
    const float* Wq  = (const float*)d_in[1];
    const float* Wk  = (const float*)d_in[2];
    const float* Wv  = (const float*)d_in[3];
    const float* Wo  = (const float*)d_in[4];
    const float* bo  = (const float*)d_in[5];
    const float* W1  = (const float*)d_in[6];
    const float* b1  = (const float*)d_in[7];
    const float* W2  = (const float*)d_in[8];
    const float* b2  = (const float*)d_in[9];
    const float* g1  = (const float*)d_in[10];
    const float* be1 = (const float*)d_in[11];
    const float* g2  = (const float*)d_in[12];
    const float* be2 = (const float*)d_in[13];
    float* out = (float*)d_out;

    const int B = 4, T = 2048;
    const int M = B * T;                         // 8192
    const size_t MC = (size_t)M * C_DIM;

    // ---- workspace layout ----
    // [qkv bf16 M*1152][att bf16 M*384]  <- h1 bf16 (M*1536) aliases both exactly
    // [y f32 MC][x1 f32 MC][weights bf16]
    char* ws = (char*)d_ws;
    unsigned short* qkv  = (unsigned short*)ws;                        // M*1152*2 = 18.9 MB
    unsigned short* att  = (unsigned short*)(ws + (size_t)M * 1152 * 2);  // M*384*2
    unsigned short* h1   = (unsigned short*)ws;                        // M*1536*2 aliases qkv+att
    char* ws2 = ws + (size_t)M * 1536 * 2;
    float* y    = (float*)ws2;                                         // MC f32
    float* x1   = (float*)(ws2 + MC * 4);                              // MC f32
    char* ws3   = ws2 + 2 * MC * 4;
    unsigned short* Wqkvb = (unsigned short*)ws3;                      // 384*1152
    unsigned short* Wob   = Wqkvb + (size_t)C_DIM * 3 * C_DIM;         // 384*384
    unsigned short* W1b   = Wob   + (size_t)C_DIM * C_DIM;             // 384*1536
    unsigned short* W2b   = W1b   + (size_t)C_DIM * FF_DIM;            // 1536*384

    dim3 blk(256);

    // ---- weight conversion ----
    pack_qkv_kernel<<<dim3((C_DIM * 3 * C_DIM + 255) / 256), blk, 0, stream>>>(Wq, Wk, Wv, Wqkvb);
    cvt_bf16_kernel<<<dim3((C_DIM * C_DIM + 255) / 256), blk, 0, stream>>>(Wo, Wob, C_DIM * C_DIM);
    cvt_bf16_kernel<<<dim3((C_DIM * FF_DIM + 255) / 256), blk, 0, stream>>>(W1, W1b, C_DIM * FF_DIM);
    cvt_bf16_kernel<<<dim3((C_DIM * FF_DIM + 255) / 256), blk, 0, stream>>>(W2, W2b, FF_DIM * C_DIM);

    // ---- qkv = x @ Wqkv  (fp32 A -> bf16 out) ----
    gemm_bf16<0, 1, 0, 0><<<dim3(3 * C_DIM / 64, M / 64), blk, 0, stream>>>(
        x, Wqkvb, nullptr, qkv, M, 3 * C_DIM, C_DIM, C_DIM, 3 * C_DIM, 3 * C_DIM);

    // ---- attention ----
    attn_mfma_kernel<<<dim3(T / 64, HEADS, B), blk, 0, stream>>>(qkv, att, T);

    // ---- y = att @ Wo + bo  (bf16 A -> f32 out) ----
    gemm_bf16<1, 0, 1, 0><<<dim3(C_DIM / 64, M / 64), blk, 0, stream>>>(
        att, Wob, bo, y, M, C_DIM, C_DIM, C_DIM, C_DIM, C_DIM);

    // ---- x1 = LN(x + y) ----
    ln_residual_kernel<<<dim3(M / 4), blk, 0, stream>>>(x, y, g1, be1, x1, M);

    // ---- h1 = relu(x1 @ W1 + b1)  (fp32 A -> bf16 out) ----
    gemm_bf16<0, 1, 1, 1><<<dim3(FF_DIM / 64, M / 64), blk, 0, stream>>>(
        x1, W1b, b1, h1, M, FF_DIM, C_DIM, C_DIM, FF_DIM, FF_DIM);

    // ---- y2 = h1 @ W2 + b2  (bf16 A -> f32 out) ----
    gemm_bf16<1, 0, 1, 0><<<dim3(C_DIM / 64, M / 64), blk, 0, stream>>>(
        h1, W2b, b2, y, M, C_DIM, FF_DIM, FF_DIM, C_DIM, C_DIM);

    // ---- out = LN(x1 + y2) ----
    ln_residual_kernel<<<dim3(M / 4), blk, 0, stream>>>(x1, y, g2, be2, out, M);
}